// Round 4
// baseline (208.667 us; speedup 1.0000x reference)
//
#include <hip/hip_runtime.h>
#include <hip/hip_bf16.h>
#include <stdint.h>
#include <stddef.h>

// Problem constants
#define BT_TOK   32768      // B*T
#define IN_DIM   512
#define OUT_DIM  512
#define QDIM     32
#define NG       8
#define NV       8
#define VD       64
#define EPS_G    1e-10f

#define MT       64         // tokens per block (= lanes per wave)
#define NW       4          // waves per block = K-split factor (K-slice = 128)

// ---------------------------------------------------------------------------
// Kernel A: paired codebook-output table
// P2[p][i*8+j][o] = cb[2p][i]@W_post[2p*64:...] + cb[2p+1][j]@W_post[...]
// bf16, 4*64*512 = 256 KB in d_ws. Rebuilt every call (ws is re-poisoned).
// ---------------------------------------------------------------------------
__global__ __launch_bounds__(256) void build_p2(
    const float* __restrict__ codebook,   // (8,8,64)
    const float* __restrict__ W_post,     // (512,512)
    __hip_bfloat16* __restrict__ P2)
{
    const int b  = blockIdx.x;     // 0..255
    const int p  = b >> 6;         // pair 0..3
    const int ij = b & 63;
    const int i  = ij >> 3, j = ij & 7;
    const int t  = threadIdx.x;    // 0..255

    const float* ca  = codebook + ((size_t)(2 * p) * NV + i) * VD;
    const float* cbp = codebook + ((size_t)(2 * p + 1) * NV + j) * VD;
    const float* wa  = W_post + (size_t)(2 * p) * VD * OUT_DIM;
    const float* wb  = W_post + (size_t)(2 * p + 1) * VD * OUT_DIM;

    float a0 = 0.f, a1 = 0.f;
#pragma unroll 8
    for (int d = 0; d < VD; ++d) {
        const float sa = ca[d];            // block-uniform -> scalar
        const float sb = cbp[d];
        a0 += sa * wa[(size_t)d * OUT_DIM + t]       + sb * wb[(size_t)d * OUT_DIM + t];
        a1 += sa * wa[(size_t)d * OUT_DIM + t + 256] + sb * wb[(size_t)d * OUT_DIM + t + 256];
    }
    __hip_bfloat16* dst = P2 + ((size_t)(p * 64 + ij)) * OUT_DIM;
    dst[t]       = __float2bfloat16(a0);
    dst[t + 256] = __float2bfloat16(a1);
}

// ---------------------------------------------------------------------------
// Kernel B: fused  h = x@W_pre+b_pre ; logits = h@W_proj+b_proj ;
//           idx = argmax(logits+gumbel(u)) ; out = b_post + gather(P2)
// Block: 256 threads = 4 waves, 64 tokens. lane = token; wave = K-quarter.
// x staged coalesced (8 dense lines / instr) into per-wave LDS buffer
// (stride-36 rows: measured conflict-free), then ds_read_b128 per-token.
// LDS ~40KB -> 4 blocks/CU = 16 waves/CU, 4 independent barrier domains.
// ---------------------------------------------------------------------------
__global__ __launch_bounds__(256, 4) void fused_main(
    const float* __restrict__ x,        // (BT,512)
    const float* __restrict__ W_pre,    // (512,32)
    const float* __restrict__ b_pre,    // (32)
    const float* __restrict__ W_proj,   // (32,64)
    const float* __restrict__ b_proj,   // (64)
    const float* __restrict__ u,        // (BT,64)
    const float* __restrict__ b_post,   // (512)
    const __hip_bfloat16* __restrict__ P2, // (4,64,512)
    float* __restrict__ out)            // (BT,512)
{
    __shared__ float Xs[NW][MT][36];    // per-wave stage buf; doubles as h partials
    __shared__ int   idxs_s[NG][MT];    // argmax per (group, token)
    __shared__ int   pidx_s[4][MT];     // paired codebook index per token

    const int t    = threadIdx.x;
    const int lane = t & 63;                                   // token within block
    const int w    = __builtin_amdgcn_readfirstlane(t >> 6);   // wave id = K-quarter
    const int tokbase = blockIdx.x * MT;
    const int gtok    = tokbase + lane;

    // ---------------- Phase 1: partial h over K-slice [w*128, w*128+128) -----
    float acc[QDIM];
#pragma unroll
    for (int j = 0; j < QDIM; ++j) acc[j] = 0.f;

    // staging role: lane covers tokens {stok, stok+8, ...}, float4 slot sf
    const int stok = lane >> 3;
    const int sf   = lane & 7;
    const float* xsl = x + (size_t)tokbase * IN_DIM + w * 128;  // this wave's K-slice

    // preload chunk 0 (8 instrs x 8 dense 128B lines each)
    float4 xg[8];
#pragma unroll
    for (int i = 0; i < 8; ++i)
        xg[i] = *(const float4*)(xsl + (size_t)(i * 8 + stok) * IN_DIM + sf * 4);

    for (int c = 0; c < 4; ++c) {                 // 4 chunks of 32 k
        // stage chunk c to this wave's LDS buffer
#pragma unroll
        for (int i = 0; i < 8; ++i)
            *(float4*)&Xs[w][i * 8 + stok][sf * 4] = xg[i];

        // prefetch chunk c+1 while computing c
        if (c < 3) {
#pragma unroll
            for (int i = 0; i < 8; ++i)
                xg[i] = *(const float4*)(xsl + (size_t)(i * 8 + stok) * IN_DIM
                                              + (c + 1) * 32 + sf * 4);
        }

        // read own token row (stride-36: conflict-free b128, in-wave lgkm order)
        float4 xr[8];
#pragma unroll
        for (int f = 0; f < 8; ++f)
            xr[f] = *(const float4*)&Xs[w][lane][f * 4];

        const float* wbase = W_pre + (size_t)(w * 128 + c * 32) * QDIM;
#pragma unroll
        for (int kk = 0; kk < 32; ++kk) {
            const float xv = ((const float*)xr)[kk];
            const float4* wr = (const float4*)(wbase + (size_t)kk * QDIM); // uniform
            const float4 w0 = wr[0], w1 = wr[1], w2 = wr[2], w3 = wr[3];
            const float4 w4 = wr[4], w5 = wr[5], w6 = wr[6], w7 = wr[7];
            acc[0]  += xv * w0.x; acc[1]  += xv * w0.y; acc[2]  += xv * w0.z; acc[3]  += xv * w0.w;
            acc[4]  += xv * w1.x; acc[5]  += xv * w1.y; acc[6]  += xv * w1.z; acc[7]  += xv * w1.w;
            acc[8]  += xv * w2.x; acc[9]  += xv * w2.y; acc[10] += xv * w2.z; acc[11] += xv * w2.w;
            acc[12] += xv * w3.x; acc[13] += xv * w3.y; acc[14] += xv * w3.z; acc[15] += xv * w3.w;
            acc[16] += xv * w4.x; acc[17] += xv * w4.y; acc[18] += xv * w4.z; acc[19] += xv * w4.w;
            acc[20] += xv * w5.x; acc[21] += xv * w5.y; acc[22] += xv * w5.z; acc[23] += xv * w5.w;
            acc[24] += xv * w6.x; acc[25] += xv * w6.y; acc[26] += xv * w6.z; acc[27] += xv * w6.w;
            acc[28] += xv * w7.x; acc[29] += xv * w7.y; acc[30] += xv * w7.z; acc[31] += xv * w7.w;
        }
    }

    __syncthreads();   // staging buffer now reused for partials
    // write partials (b128; stride-36 layout measured conflict-free)
#pragma unroll
    for (int j4 = 0; j4 < 8; ++j4)
        *(float4*)&Xs[w][lane][j4 * 4] =
            make_float4(acc[j4 * 4], acc[j4 * 4 + 1], acc[j4 * 4 + 2], acc[j4 * 4 + 3]);
    __syncthreads();

    // reduce 4 K-slices in place (each cell owned by exactly one thread)
#pragma unroll
    for (int r = 0; r < 8; ++r) {
        const int id  = t + 256 * r;          // 2048 (tok,j) cells
        const int tok = id >> 5;
        const int j   = id & 31;
        const float h = b_pre[j] + Xs[0][tok][j] + Xs[1][tok][j]
                                 + Xs[2][tok][j] + Xs[3][tok][j];
        Xs[0][tok][j] = h;
    }
    __syncthreads();

    // ---------------- Phase 2: logits + gumbel + argmax (wave w -> groups 2w,2w+1)
    float h[QDIM];
#pragma unroll
    for (int j4 = 0; j4 < 8; ++j4) {
        const float4 v = *(const float4*)&Xs[0][lane][j4 * 4];
        h[j4 * 4] = v.x; h[j4 * 4 + 1] = v.y; h[j4 * 4 + 2] = v.z; h[j4 * 4 + 3] = v.w;
    }

#pragma unroll
    for (int gg = 0; gg < 2; ++gg) {
        const int g = 2 * w + gg;                       // wave-uniform
        const float4 b0 = *(const float4*)&b_proj[g * 8];
        const float4 b1 = *(const float4*)&b_proj[g * 8 + 4];
        float lg[8] = {b0.x, b0.y, b0.z, b0.w, b1.x, b1.y, b1.z, b1.w};

#pragma unroll
        for (int j = 0; j < QDIM; ++j) {
            const float hv = h[j];
            const float4 a0 = *(const float4*)&W_proj[(size_t)j * 64 + g * 8];     // uniform
            const float4 a1 = *(const float4*)&W_proj[(size_t)j * 64 + g * 8 + 4]; // uniform
            lg[0] += hv * a0.x; lg[1] += hv * a0.y; lg[2] += hv * a0.z; lg[3] += hv * a0.w;
            lg[4] += hv * a1.x; lg[5] += hv * a1.y; lg[6] += hv * a1.z; lg[7] += hv * a1.w;
        }

        const float4 u0 = *(const float4*)&u[(size_t)gtok * 64 + g * 8];
        const float4 u1 = *(const float4*)&u[(size_t)gtok * 64 + g * 8 + 4];
        float y[8];
        y[0] = lg[0] - logf(-logf(u0.x + EPS_G) + EPS_G);
        y[1] = lg[1] - logf(-logf(u0.y + EPS_G) + EPS_G);
        y[2] = lg[2] - logf(-logf(u0.z + EPS_G) + EPS_G);
        y[3] = lg[3] - logf(-logf(u0.w + EPS_G) + EPS_G);
        y[4] = lg[4] - logf(-logf(u1.x + EPS_G) + EPS_G);
        y[5] = lg[5] - logf(-logf(u1.y + EPS_G) + EPS_G);
        y[6] = lg[6] - logf(-logf(u1.z + EPS_G) + EPS_G);
        y[7] = lg[7] - logf(-logf(u1.w + EPS_G) + EPS_G);

        float best = y[0];
        int bi = 0;
#pragma unroll
        for (int v = 1; v < 8; ++v)
            if (y[v] > best) { best = y[v]; bi = v; }   // strict > == np first-max
        idxs_s[g][lane] = bi;
    }
    __syncthreads();

    // pair indices: pidx[p][tok] = idx[2p]*8 + idx[2p+1]  (256 entries, 256 thr)
    {
        const int p = t >> 6, tok = t & 63;
        pidx_s[p][tok] = idxs_s[2 * p][tok] * 8 + idxs_s[2 * p + 1][tok];
    }
    __syncthreads();

    // ---------------- Phase 3: out = b_post + sum_p P2[p][pidx] --------------
    // wave-uniform token per wave; 8B gathers (512B/wave contiguous, L2-resident),
    // float4 stores (1KB/wave dense).
    const int half = t >> 7;             // token parity
    const int tt   = t & 127;            // float4 slot in row
    const int o4   = tt * 4;
    const float4 bp = *(const float4*)&b_post[o4];
    const uint2* p2v = (const uint2*)P2;  // 8B = 4 bf16; row = (p*64+pi)*128 + tt

#pragma unroll 4
    for (int it = 0; it < 32; ++it) {
        const int tok = 2 * it + half;
        const int p0 = pidx_s[0][tok];
        const int p1 = pidx_s[1][tok];
        const int p2i = pidx_s[2][tok];
        const int p3 = pidx_s[3][tok];
        const uint2 r0 = p2v[(size_t)(0 * 64 + p0) * 128 + tt];
        const uint2 r1 = p2v[(size_t)(1 * 64 + p1) * 128 + tt];
        const uint2 r2 = p2v[(size_t)(2 * 64 + p2i) * 128 + tt];
        const uint2 r3 = p2v[(size_t)(3 * 64 + p3) * 128 + tt];
        float4 s = bp;
        s.x += __uint_as_float(r0.x << 16); s.y += __uint_as_float(r0.x & 0xffff0000u);
        s.z += __uint_as_float(r0.y << 16); s.w += __uint_as_float(r0.y & 0xffff0000u);
        s.x += __uint_as_float(r1.x << 16); s.y += __uint_as_float(r1.x & 0xffff0000u);
        s.z += __uint_as_float(r1.y << 16); s.w += __uint_as_float(r1.y & 0xffff0000u);
        s.x += __uint_as_float(r2.x << 16); s.y += __uint_as_float(r2.x & 0xffff0000u);
        s.z += __uint_as_float(r2.y << 16); s.w += __uint_as_float(r2.y & 0xffff0000u);
        s.x += __uint_as_float(r3.x << 16); s.y += __uint_as_float(r3.x & 0xffff0000u);
        s.z += __uint_as_float(r3.y << 16); s.w += __uint_as_float(r3.y & 0xffff0000u);
        *(float4*)&out[(size_t)(tokbase + tok) * OUT_DIM + o4] = s;
    }
}

// ---------------------------------------------------------------------------
extern "C" void kernel_launch(void* const* d_in, const int* in_sizes, int n_in,
                              void* d_out, int out_size, void* d_ws, size_t ws_size,
                              hipStream_t stream) {
    const float* x        = (const float*)d_in[0];
    const float* W_pre    = (const float*)d_in[1];
    const float* b_pre    = (const float*)d_in[2];
    const float* W_proj   = (const float*)d_in[3];
    const float* b_proj   = (const float*)d_in[4];
    const float* codebook = (const float*)d_in[5];
    const float* W_post   = (const float*)d_in[6];
    const float* b_post   = (const float*)d_in[7];
    const float* u        = (const float*)d_in[8];
    float* out = (float*)d_out;

    __hip_bfloat16* P2 = (__hip_bfloat16*)d_ws;   // 256 KB

    build_p2<<<256, 256, 0, stream>>>(codebook, W_post, P2);
    fused_main<<<BT_TOK / MT, 256, 0, stream>>>(x, W_pre, b_pre, W_proj, b_proj,
                                                u, b_post, P2, out);
}